// Round 7
// baseline (705.945 us; speedup 1.0000x reference)
//
#include <hip/hip_runtime.h>
#include <hip/hip_bf16.h>
#include <math.h>

// ---------------------------------------------------------------------------
// GCN forward: out = log_softmax( A@( relu(A@(x@W1)+b1) @ W2 ) + b2 )
// Round 7: spmm1 -> XCD-pinned 16-dim panels (panel = blockIdx.x % 8 rides the
// XCD round-robin; 3.2 MB panel table fits one XCD's 4 MiB L2 -> gathers become
// L2 hits; edges re-streamed 8x). sup1 stored panel-major [8][N][16] by gemm1.
// spmm2 reverted to R4's 3-rows/wave version (R6 variant was -27us worse).
// ---------------------------------------------------------------------------

#define GCN_NFEAT 256
#define GCN_NHID  128
#define GCN_NCLASS 40

typedef __bf16 bf16_t;
typedef bf16_t bf16x8 __attribute__((ext_vector_type(8)));
typedef float  f32x4  __attribute__((ext_vector_type(4)));

static __device__ __forceinline__ unsigned short f2b(float f) {
    bf16_t b = (bf16_t)f;
    return *(unsigned short*)&b;
}
static __device__ __forceinline__ float blo(unsigned int u) {
    return __uint_as_float(u << 16);
}
static __device__ __forceinline__ float bhi(unsigned int u) {
    return __uint_as_float(u & 0xffff0000u);
}

// ---- row_ptr[r] = lower_bound(adj_row, r), r in [0, N] ---------------------
__global__ __launch_bounds__(256) void k_row_ptr(
    const int* __restrict__ row, int* __restrict__ row_ptr, int n_rows, int n_edges)
{
    int r = blockIdx.x * blockDim.x + threadIdx.x;
    if (r > n_rows) return;
    int lo = 0, hi = n_edges;
    while (lo < hi) {
        int mid = (lo + hi) >> 1;
        if (row[mid] < r) lo = mid + 1; else hi = mid;
    }
    row_ptr[r] = lo;
}

// ---- prep: W1t_bf16[128][256] = bf16(W1[k][c]) transposed ------------------
__global__ __launch_bounds__(256) void k_prep_w1t(
    const float* __restrict__ w1, bf16_t* __restrict__ w1t)
{
    int idx = blockIdx.x * 256 + threadIdx.x;           // 128*256 total
    int c = idx & 127;
    int k = idx >> 7;
    w1t[(size_t)c * GCN_NFEAT + k] = (bf16_t)w1[(size_t)k * GCN_NHID + c];
}

// ---- prep: W2t_bf16[48][128], cols 40..47 zero -----------------------------
__global__ __launch_bounds__(256) void k_prep_w2t(
    const float* __restrict__ w2, bf16_t* __restrict__ w2t)
{
    int idx = blockIdx.x * 256 + threadIdx.x;           // 48*128 = 6144 total
    if (idx >= 48 * GCN_NHID) return;
    int c = idx / GCN_NHID;
    int k = idx - c * GCN_NHID;
    float v = (c < GCN_NCLASS) ? w2[(size_t)k * GCN_NCLASS + c] : 0.f;
    w2t[idx] = (bf16_t)v;
}

// ---- GEMM1 (MFMA): sup1p[8][N][16] = bf16( x[N,256] @ W1 ), panel-major ----
__global__ __launch_bounds__(256) void k_gemm1(
    const float* __restrict__ x, const bf16_t* __restrict__ w1t,
    bf16_t* __restrict__ out, int nrows)
{
    __shared__ __align__(16) bf16_t As[128][72];   // [row][k]
    __shared__ __align__(16) bf16_t Bs[128][72];   // [col][k]

    const int tid  = threadIdx.x;
    const int wave = tid >> 6, lane = tid & 63;
    const int wm = wave >> 1, wn = wave & 1;
    const int lm = lane & 15, quad = lane >> 4;
    const int r0 = blockIdx.x * 128;

    f32x4 acc[4][4] = {};

    for (int k0 = 0; k0 < GCN_NFEAT; k0 += 64) {
        {
            const int row = tid >> 1, half = tid & 1;
            const int gr = r0 + row;
            union { bf16_t b[32]; uint4 q[4]; } t;
            if (gr < nrows) {
                const float* p = x + (size_t)gr * GCN_NFEAT + k0 + half * 32;
#pragma unroll
                for (int i = 0; i < 8; i++) {
                    float4 v = ((const float4*)p)[i];
                    t.b[i*4+0] = (bf16_t)v.x; t.b[i*4+1] = (bf16_t)v.y;
                    t.b[i*4+2] = (bf16_t)v.z; t.b[i*4+3] = (bf16_t)v.w;
                }
            } else {
#pragma unroll
                for (int i = 0; i < 4; i++) t.q[i] = make_uint4(0,0,0,0);
            }
            uint4* dst = (uint4*)&As[row][half * 32];
#pragma unroll
            for (int i = 0; i < 4; i++) dst[i] = t.q[i];
        }
        {
            const int colc = tid >> 1, half = tid & 1;
            const uint4* src = (const uint4*)(w1t + (size_t)colc * GCN_NFEAT + k0 + half * 32);
            uint4* dst = (uint4*)&Bs[colc][half * 32];
#pragma unroll
            for (int i = 0; i < 4; i++) dst[i] = src[i];
        }
        __syncthreads();

#pragma unroll
        for (int ks = 0; ks < 2; ks++) {
            bf16x8 af[4], bfr[4];
#pragma unroll
            for (int i = 0; i < 4; i++)
                af[i] = *(const bf16x8*)&As[wm*64 + i*16 + lm][ks*32 + quad*8];
#pragma unroll
            for (int j = 0; j < 4; j++)
                bfr[j] = *(const bf16x8*)&Bs[wn*64 + j*16 + lm][ks*32 + quad*8];
#pragma unroll
            for (int i = 0; i < 4; i++)
#pragma unroll
                for (int j = 0; j < 4; j++)
                    acc[i][j] = __builtin_amdgcn_mfma_f32_16x16x32_bf16(
                        af[i], bfr[j], acc[i][j], 0, 0, 0);
        }
        __syncthreads();
    }

    // store panel-major: element (gr, gc) -> out[((gc>>4)*N + gr)*16 + (gc&15)]
    // gc = wn*64 + j*16 + lm  =>  panel p = wn*4 + j, dim d = lm.
#pragma unroll
    for (int i = 0; i < 4; i++) {
#pragma unroll
        for (int reg = 0; reg < 4; reg++) {
            const int gr = r0 + wm*64 + i*16 + quad*4 + reg;
            if (gr < nrows) {
#pragma unroll
                for (int j = 0; j < 4; j++) {
                    const int p = wn*4 + j;
                    out[((size_t)p * nrows + gr) * 16 + lm] = (bf16_t)acc[i][j][reg];
                }
            }
        }
    }
}

// ---- spmm1 (panelized): h[r, p*16..p*16+15] for panel p = blockIdx.x % 8 ---
// Wave per (row, panel). eg = lane>>3 owns edge slot, li = lane&7 owns one
// uint (2 dims) of the 32 B panel row -> 8 edges per gather instruction.
// 32-edge chunks: col/val loaded once by lanes (lane&31), shfl-broadcast.
__global__ __launch_bounds__(256) void k_spmm1(
    const int* __restrict__ row_ptr, const int* __restrict__ col,
    const float* __restrict__ val, const unsigned int* __restrict__ sup1p,
    const float* __restrict__ b1, unsigned int* __restrict__ h, int nrows)
{
    const int p     = blockIdx.x & 7;       // panel == XCD (round-robin dispatch)
    const int chunk = blockIdx.x >> 3;
    const int wave  = threadIdx.x >> 6;
    const int lane  = threadIdx.x & 63;
    const int r     = chunk * 4 + wave;
    if (r >= nrows) return;

    const int eg = lane >> 3;               // edge slot 0..7
    const int li = lane & 7;                // uint within the 32 B panel row
    const unsigned int* sp = sup1p + (size_t)p * nrows * 8;

    const int e0 = row_ptr[r];
    const int e1 = row_ptr[r + 1];

    float ax = 0.f, ay = 0.f;
    int e = e0;
    for (; e + 32 <= e1; e += 32) {
        const int   cv = __builtin_nontemporal_load(&col[e + (lane & 31)]);
        const float vv = __builtin_nontemporal_load(&val[e + (lane & 31)]);
#pragma unroll
        for (int s = 0; s < 4; s++) {
            const int   cj = __shfl(cv, s * 8 + eg, 64);
            const float vj = __shfl(vv, s * 8 + eg, 64);
            const unsigned int u = sp[(unsigned)cj * 8u + li];
            ax = fmaf(vj, blo(u), ax);
            ay = fmaf(vj, bhi(u), ay);
        }
    }
    // tail: group eg takes edges e+eg, e+eg+8, ...
    for (int k = e + eg; k < e1; k += 8) {
        const int   c = col[k];
        const float v = val[k];
        const unsigned int u = sp[(unsigned)c * 8u + li];
        ax = fmaf(v, blo(u), ax);
        ay = fmaf(v, bhi(u), ay);
    }

    // reduce across the 8 edge groups (xor folds 8,16,32)
    ax += __shfl_xor(ax, 8, 64);  ay += __shfl_xor(ay, 8, 64);
    ax += __shfl_xor(ax, 16, 64); ay += __shfl_xor(ay, 16, 64);
    ax += __shfl_xor(ax, 32, 64); ay += __shfl_xor(ay, 32, 64);

    if (lane < 8) {
        const float2 bb = *(const float2*)(b1 + p * 16 + li * 2);
        const float ox = fmaxf(ax + bb.x, 0.f);
        const float oy = fmaxf(ay + bb.y, 0.f);
        const unsigned int pk = (unsigned int)f2b(ox) | ((unsigned int)f2b(oy) << 16);
        h[(unsigned)r * 64u + (unsigned)p * 8u + li] = pk;   // h row-major [N][128]
    }
}

// ---- GEMM2 (MFMA): sup2_bf16[N,40] = bf16( h[N,128] @ W2 ) -----------------
__global__ __launch_bounds__(256) void k_gemm2(
    const bf16_t* __restrict__ h, const bf16_t* __restrict__ w2t,
    bf16_t* __restrict__ out, int nrows)
{
    __shared__ __align__(16) bf16_t As[128][136];  // [row][k]
    __shared__ __align__(16) bf16_t Bs[48][136];   // [col][k]

    const int tid  = threadIdx.x;
    const int wave = tid >> 6, lane = tid & 63;
    const int lm = lane & 15, quad = lane >> 4;
    const int r0 = blockIdx.x * 128;

    {
        const int row = tid >> 1, half = tid & 1;
        const int gr = r0 + row;
        uint4* dst = (uint4*)&As[row][half * 64];
        if (gr < nrows) {
            const uint4* src = (const uint4*)(h + (size_t)gr * GCN_NHID + half * 64);
#pragma unroll
            for (int i = 0; i < 8; i++) dst[i] = src[i];
        } else {
#pragma unroll
            for (int i = 0; i < 8; i++) dst[i] = make_uint4(0,0,0,0);
        }
    }
    for (int idx = tid; idx < 48 * 16; idx += 256) {
        const int c = idx >> 4, seg = idx & 15;
        ((uint4*)&Bs[c][0])[seg] = ((const uint4*)(w2t + (size_t)c * GCN_NHID))[seg];
    }
    __syncthreads();

    f32x4 acc[2][3] = {};
#pragma unroll
    for (int ks = 0; ks < 4; ks++) {
        bf16x8 af[2], bfr[3];
#pragma unroll
        for (int i = 0; i < 2; i++)
            af[i] = *(const bf16x8*)&As[wave*32 + i*16 + lm][ks*32 + quad*8];
#pragma unroll
        for (int j = 0; j < 3; j++)
            bfr[j] = *(const bf16x8*)&Bs[j*16 + lm][ks*32 + quad*8];
#pragma unroll
        for (int i = 0; i < 2; i++)
#pragma unroll
            for (int j = 0; j < 3; j++)
                acc[i][j] = __builtin_amdgcn_mfma_f32_16x16x32_bf16(
                    af[i], bfr[j], acc[i][j], 0, 0, 0);
    }

#pragma unroll
    for (int i = 0; i < 2; i++) {
#pragma unroll
        for (int reg = 0; reg < 4; reg++) {
            const int gr = r0 + wave*32 + i*16 + quad*4 + reg;
            if (gr < nrows) {
#pragma unroll
                for (int j = 0; j < 3; j++) {
                    const int gc = j*16 + lm;
                    if (gc < GCN_NCLASS)
                        out[(size_t)gr * GCN_NCLASS + gc] = (bf16_t)acc[i][j][reg];
                }
            }
        }
    }
}

// ---- spmm2 + bias + log_softmax -> out[N,40] fp32 (R4 version) -------------
// 3 rows per wave: group g = lane/20 handles row wid*3+g, li = lane%20 owns
// classes {2li, 2li+1} packed in one uint. One load instr serves all 3 groups.
__global__ __launch_bounds__(256) void k_spmm2_lsm(
    const int* __restrict__ row_ptr, const int* __restrict__ col,
    const float* __restrict__ val, const unsigned int* __restrict__ sup2,
    const float* __restrict__ b2, float* __restrict__ out, int nrows)
{
    const int wid  = (blockIdx.x * blockDim.x + threadIdx.x) >> 6;
    const int lane = threadIdx.x & 63;
    const int g    = lane / 20;            // 0..2 valid, 3 = idle lanes 60-63
    const int li   = lane - g * 20;
    const int r    = wid * 3 + g;
    const bool active = (g < 3) && (r < nrows);

    int e0 = 0, e1 = 0;
    if (active) { e0 = row_ptr[r]; e1 = row_ptr[r + 1]; }

    float ax = 0.f, ay = 0.f;
    int e = e0;
    for (; e + 3 < e1; e += 4) {
        const int c0 = col[e],   c1 = col[e+1], c2 = col[e+2], c3 = col[e+3];
        const float v0 = val[e], v1 = val[e+1], v2 = val[e+2], v3 = val[e+3];
        const unsigned int u0 = sup2[(unsigned)(c0 * 20) + li];
        const unsigned int u1 = sup2[(unsigned)(c1 * 20) + li];
        const unsigned int u2 = sup2[(unsigned)(c2 * 20) + li];
        const unsigned int u3 = sup2[(unsigned)(c3 * 20) + li];
        ax = fmaf(v0, blo(u0), ax); ay = fmaf(v0, bhi(u0), ay);
        ax = fmaf(v1, blo(u1), ax); ay = fmaf(v1, bhi(u1), ay);
        ax = fmaf(v2, blo(u2), ax); ay = fmaf(v2, bhi(u2), ay);
        ax = fmaf(v3, blo(u3), ax); ay = fmaf(v3, bhi(u3), ay);
    }
    for (; e < e1; e++) {
        const unsigned int u = sup2[(unsigned)(col[e] * 20) + li];
        const float v = val[e];
        ax = fmaf(v, blo(u), ax); ay = fmaf(v, bhi(u), ay);
    }

    float l0 = -INFINITY, l1 = -INFINITY;
    if (active) {
        l0 = ax + b2[li * 2];
        l1 = ay + b2[li * 2 + 1];
    }

    // group-local (20-lane) shuffle reductions
    float m = fmaxf(l0, l1);
#pragma unroll
    for (int off = 16; off >= 1; off >>= 1) {
        const float t = __shfl_down(m, off, 64);
        if (li + off < 20) m = fmaxf(m, t);
    }
    m = __shfl(m, g * 20, 64);   // broadcast group max

    float s = active ? (__expf(l0 - m) + __expf(l1 - m)) : 0.f;
#pragma unroll
    for (int off = 16; off >= 1; off >>= 1) {
        const float t = __shfl_down(s, off, 64);
        if (li + off < 20) s += t;
    }
    s = __shfl(s, g * 20, 64);

    if (active) {
        const float lse = m + __logf(s);
        float* p = out + (size_t)r * GCN_NCLASS + li * 2;
        p[0] = l0 - lse;
        p[1] = l1 - lse;
    }
}

// ---------------------------------------------------------------------------
extern "C" void kernel_launch(void* const* d_in, const int* in_sizes, int n_in,
                              void* d_out, int out_size, void* d_ws, size_t ws_size,
                              hipStream_t stream)
{
    const float* x       = (const float*)d_in[0];
    const int*   adj_row = (const int*)  d_in[1];
    const int*   adj_col = (const int*)  d_in[2];
    const float* adj_val = (const float*)d_in[3];
    // d_in[4] = i (unused)
    const float* W1 = (const float*)d_in[5];
    const float* b1 = (const float*)d_in[6];
    const float* W2 = (const float*)d_in[7];
    const float* b2 = (const float*)d_in[8];
    float* out = (float*)d_out;

    const int N = in_sizes[0] / GCN_NFEAT;   // 100000
    const int E = in_sizes[1];               // 3200000

    // workspace layout (1 KiB aligned chunks)
    char* ws = (char*)d_ws;
    size_t off = 0;
    int* row_ptr = (int*)(ws + off);
    off += (((size_t)(N + 1) * sizeof(int)) + 1023) & ~(size_t)1023;
    bf16_t* w1t = (bf16_t*)(ws + off);                 // 128*256 bf16
    off += ((size_t)GCN_NHID * GCN_NFEAT * 2 + 1023) & ~(size_t)1023;
    bf16_t* w2t = (bf16_t*)(ws + off);                 // 48*128 bf16
    off += ((size_t)48 * GCN_NHID * 2 + 1023) & ~(size_t)1023;
    bf16_t* sup1p = (bf16_t*)(ws + off);               // [8][N][16] bf16 panel-major
    off += ((size_t)N * GCN_NHID * 2 + 1023) & ~(size_t)1023;
    bf16_t* h = (bf16_t*)(ws + off);                   // N*128 bf16 row-major
    bf16_t* sup2 = sup1p;                              // reuse sup1p region (N*40 bf16)

    k_row_ptr<<<(N + 1 + 255) / 256, 256, 0, stream>>>(adj_row, row_ptr, N, E);
    k_prep_w1t<<<GCN_NHID * GCN_NFEAT / 256, 256, 0, stream>>>(W1, w1t);
    k_prep_w2t<<<(48 * GCN_NHID + 255) / 256, 256, 0, stream>>>(W2, w2t);
    k_gemm1<<<(N + 127) / 128, 256, 0, stream>>>(x, w1t, sup1p, N);
    const int nblk1 = ((N + 3) / 4) * 8;               // (row-chunk, panel) blocks
    k_spmm1<<<nblk1, 256, 0, stream>>>(row_ptr, adj_col, adj_val,
                                       (const unsigned int*)sup1p, b1,
                                       (unsigned int*)h, N);
    k_gemm2<<<(N + 127) / 128, 256, 0, stream>>>(h, w2t, sup2, N);
    const int nw2 = (N + 2) / 3;                       // waves for spmm2 (3 rows/wave)
    k_spmm2_lsm<<<(nw2 + 3) / 4, 256, 0, stream>>>(row_ptr, adj_col, adj_val,
                                                   (const unsigned int*)sup2, b2, out, N);
}

// Round 8
// 569.873 us; speedup vs baseline: 1.2388x; 1.2388x over previous
//
#include <hip/hip_runtime.h>
#include <hip/hip_bf16.h>
#include <math.h>

// ---------------------------------------------------------------------------
// GCN forward: out = log_softmax( A@( relu(A@(x@W1)+b1) @ W2 ) + b2 )
// Round 8: keep XCD-pinned 16-dim panels for spmm1 (R7 proved table goes
// L2-resident: FETCH 374->185 MB) but fix the latency serialization:
// masked 32-edge chunks (index clamp + val=0), NO strided tail loop, no
// nt-hints on col/val. spmm2 = R4 3-rows/wave. gemm1 panel-major store.
// ---------------------------------------------------------------------------

#define GCN_NFEAT 256
#define GCN_NHID  128
#define GCN_NCLASS 40

typedef __bf16 bf16_t;
typedef bf16_t bf16x8 __attribute__((ext_vector_type(8)));
typedef float  f32x4  __attribute__((ext_vector_type(4)));

static __device__ __forceinline__ unsigned short f2b(float f) {
    bf16_t b = (bf16_t)f;
    return *(unsigned short*)&b;
}
static __device__ __forceinline__ float blo(unsigned int u) {
    return __uint_as_float(u << 16);
}
static __device__ __forceinline__ float bhi(unsigned int u) {
    return __uint_as_float(u & 0xffff0000u);
}

// ---- row_ptr[r] = lower_bound(adj_row, r), r in [0, N] ---------------------
__global__ __launch_bounds__(256) void k_row_ptr(
    const int* __restrict__ row, int* __restrict__ row_ptr, int n_rows, int n_edges)
{
    int r = blockIdx.x * blockDim.x + threadIdx.x;
    if (r > n_rows) return;
    int lo = 0, hi = n_edges;
    while (lo < hi) {
        int mid = (lo + hi) >> 1;
        if (row[mid] < r) lo = mid + 1; else hi = mid;
    }
    row_ptr[r] = lo;
}

// ---- prep: W1t_bf16[128][256] = bf16(W1[k][c]) transposed ------------------
__global__ __launch_bounds__(256) void k_prep_w1t(
    const float* __restrict__ w1, bf16_t* __restrict__ w1t)
{
    int idx = blockIdx.x * 256 + threadIdx.x;           // 128*256 total
    int c = idx & 127;
    int k = idx >> 7;
    w1t[(size_t)c * GCN_NFEAT + k] = (bf16_t)w1[(size_t)k * GCN_NHID + c];
}

// ---- prep: W2t_bf16[48][128], cols 40..47 zero -----------------------------
__global__ __launch_bounds__(256) void k_prep_w2t(
    const float* __restrict__ w2, bf16_t* __restrict__ w2t)
{
    int idx = blockIdx.x * 256 + threadIdx.x;           // 48*128 = 6144 total
    if (idx >= 48 * GCN_NHID) return;
    int c = idx / GCN_NHID;
    int k = idx - c * GCN_NHID;
    float v = (c < GCN_NCLASS) ? w2[(size_t)k * GCN_NCLASS + c] : 0.f;
    w2t[idx] = (bf16_t)v;
}

// ---- GEMM1 (MFMA): sup1p[8][N][16] = bf16( x[N,256] @ W1 ), panel-major ----
__global__ __launch_bounds__(256) void k_gemm1(
    const float* __restrict__ x, const bf16_t* __restrict__ w1t,
    bf16_t* __restrict__ out, int nrows)
{
    __shared__ __align__(16) bf16_t As[128][72];   // [row][k]
    __shared__ __align__(16) bf16_t Bs[128][72];   // [col][k]

    const int tid  = threadIdx.x;
    const int wave = tid >> 6, lane = tid & 63;
    const int wm = wave >> 1, wn = wave & 1;
    const int lm = lane & 15, quad = lane >> 4;
    const int r0 = blockIdx.x * 128;

    f32x4 acc[4][4] = {};

    for (int k0 = 0; k0 < GCN_NFEAT; k0 += 64) {
        {
            const int row = tid >> 1, half = tid & 1;
            const int gr = r0 + row;
            union { bf16_t b[32]; uint4 q[4]; } t;
            if (gr < nrows) {
                const float* p = x + (size_t)gr * GCN_NFEAT + k0 + half * 32;
#pragma unroll
                for (int i = 0; i < 8; i++) {
                    float4 v = ((const float4*)p)[i];
                    t.b[i*4+0] = (bf16_t)v.x; t.b[i*4+1] = (bf16_t)v.y;
                    t.b[i*4+2] = (bf16_t)v.z; t.b[i*4+3] = (bf16_t)v.w;
                }
            } else {
#pragma unroll
                for (int i = 0; i < 4; i++) t.q[i] = make_uint4(0,0,0,0);
            }
            uint4* dst = (uint4*)&As[row][half * 32];
#pragma unroll
            for (int i = 0; i < 4; i++) dst[i] = t.q[i];
        }
        {
            const int colc = tid >> 1, half = tid & 1;
            const uint4* src = (const uint4*)(w1t + (size_t)colc * GCN_NFEAT + k0 + half * 32);
            uint4* dst = (uint4*)&Bs[colc][half * 32];
#pragma unroll
            for (int i = 0; i < 4; i++) dst[i] = src[i];
        }
        __syncthreads();

#pragma unroll
        for (int ks = 0; ks < 2; ks++) {
            bf16x8 af[4], bfr[4];
#pragma unroll
            for (int i = 0; i < 4; i++)
                af[i] = *(const bf16x8*)&As[wm*64 + i*16 + lm][ks*32 + quad*8];
#pragma unroll
            for (int j = 0; j < 4; j++)
                bfr[j] = *(const bf16x8*)&Bs[wn*64 + j*16 + lm][ks*32 + quad*8];
#pragma unroll
            for (int i = 0; i < 4; i++)
#pragma unroll
                for (int j = 0; j < 4; j++)
                    acc[i][j] = __builtin_amdgcn_mfma_f32_16x16x32_bf16(
                        af[i], bfr[j], acc[i][j], 0, 0, 0);
        }
        __syncthreads();
    }

    // store panel-major: (gr, gc) -> out[((gc>>4)*N + gr)*16 + (gc&15)]
#pragma unroll
    for (int i = 0; i < 4; i++) {
#pragma unroll
        for (int reg = 0; reg < 4; reg++) {
            const int gr = r0 + wm*64 + i*16 + quad*4 + reg;
            if (gr < nrows) {
#pragma unroll
                for (int j = 0; j < 4; j++) {
                    const int p = wn*4 + j;
                    out[((size_t)p * nrows + gr) * 16 + lm] = (bf16_t)acc[i][j][reg];
                }
            }
        }
    }
}

// ---- spmm1 (panelized, masked chunks): h[r, p*16..p*16+15] -----------------
// panel p = blockIdx.x % 8 rides XCD round-robin -> 3.2 MB panel table stays
// L2-resident. Wave per (row, panel). Chunk = 32 edges, index-clamped and
// val-masked (NO tail loop): 4 independent gathers in flight per chunk.
// eg = lane>>3 owns edge slot, li = lane&7 owns 4 dims (one uint = 2 bf16x2).
__global__ __launch_bounds__(256) void k_spmm1(
    const int* __restrict__ row_ptr, const int* __restrict__ col,
    const float* __restrict__ val, const unsigned int* __restrict__ sup1p,
    const float* __restrict__ b1, unsigned int* __restrict__ h, int nrows)
{
    const int p     = blockIdx.x & 7;       // panel == XCD (round-robin dispatch)
    const int chunk = blockIdx.x >> 3;
    const int wave  = threadIdx.x >> 6;
    const int lane  = threadIdx.x & 63;
    const int r     = chunk * 4 + wave;
    if (r >= nrows) return;

    const int eg = lane >> 3;               // edge slot 0..7
    const int li = lane & 7;                // uint within the 32 B panel row
    const int sl = lane & 31;               // edge-stream loader index
    const unsigned int* sp = sup1p + (size_t)p * nrows * 8;

    const int e0 = row_ptr[r];
    const int e1 = row_ptr[r + 1];
    const int ilim = e1 - 1;

    float ax = 0.f, ay = 0.f;
    for (int e = e0; e < e1; e += 32) {
        const int ke  = e + sl;
        const int idx = (ke <= ilim) ? ke : ilim;
        const int   cv = col[idx];
        const float vv = (ke <= ilim) ? val[idx] : 0.f;
#pragma unroll
        for (int s = 0; s < 4; s++) {
            const int   cj = __shfl(cv, s * 8 + eg, 64);
            const float vj = __shfl(vv, s * 8 + eg, 64);
            const unsigned int u = sp[(unsigned)cj * 8u + li];
            ax = fmaf(vj, blo(u), ax);
            ay = fmaf(vj, bhi(u), ay);
        }
    }

    // reduce across the 8 edge slots (fold 8,16,32)
    ax += __shfl_xor(ax, 8, 64);  ay += __shfl_xor(ay, 8, 64);
    ax += __shfl_xor(ax, 16, 64); ay += __shfl_xor(ay, 16, 64);
    ax += __shfl_xor(ax, 32, 64); ay += __shfl_xor(ay, 32, 64);

    if (lane < 8) {
        const float2 bb = *(const float2*)(b1 + p * 16 + li * 2);
        const float ox = fmaxf(ax + bb.x, 0.f);
        const float oy = fmaxf(ay + bb.y, 0.f);
        const unsigned int pk = (unsigned int)f2b(ox) | ((unsigned int)f2b(oy) << 16);
        h[(unsigned)r * 64u + (unsigned)p * 8u + li] = pk;   // h row-major [N][128]
    }
}

// ---- GEMM2 (MFMA): sup2_bf16[N,40] = bf16( h[N,128] @ W2 ) -----------------
__global__ __launch_bounds__(256) void k_gemm2(
    const bf16_t* __restrict__ h, const bf16_t* __restrict__ w2t,
    bf16_t* __restrict__ out, int nrows)
{
    __shared__ __align__(16) bf16_t As[128][136];  // [row][k]
    __shared__ __align__(16) bf16_t Bs[48][136];   // [col][k]

    const int tid  = threadIdx.x;
    const int wave = tid >> 6, lane = tid & 63;
    const int lm = lane & 15, quad = lane >> 4;
    const int r0 = blockIdx.x * 128;

    {
        const int row = tid >> 1, half = tid & 1;
        const int gr = r0 + row;
        uint4* dst = (uint4*)&As[row][half * 64];
        if (gr < nrows) {
            const uint4* src = (const uint4*)(h + (size_t)gr * GCN_NHID + half * 64);
#pragma unroll
            for (int i = 0; i < 8; i++) dst[i] = src[i];
        } else {
#pragma unroll
            for (int i = 0; i < 8; i++) dst[i] = make_uint4(0,0,0,0);
        }
    }
    for (int idx = tid; idx < 48 * 16; idx += 256) {
        const int c = idx >> 4, seg = idx & 15;
        ((uint4*)&Bs[c][0])[seg] = ((const uint4*)(w2t + (size_t)c * GCN_NHID))[seg];
    }
    __syncthreads();

    f32x4 acc[2][3] = {};
#pragma unroll
    for (int ks = 0; ks < 4; ks++) {
        bf16x8 af[2], bfr[3];
#pragma unroll
        for (int i = 0; i < 2; i++)
            af[i] = *(const bf16x8*)&As[wave*32 + i*16 + lm][ks*32 + quad*8];
#pragma unroll
        for (int j = 0; j < 3; j++)
            bfr[j] = *(const bf16x8*)&Bs[j*16 + lm][ks*32 + quad*8];
#pragma unroll
        for (int i = 0; i < 2; i++)
#pragma unroll
            for (int j = 0; j < 3; j++)
                acc[i][j] = __builtin_amdgcn_mfma_f32_16x16x32_bf16(
                    af[i], bfr[j], acc[i][j], 0, 0, 0);
    }

#pragma unroll
    for (int i = 0; i < 2; i++) {
#pragma unroll
        for (int reg = 0; reg < 4; reg++) {
            const int gr = r0 + wave*32 + i*16 + quad*4 + reg;
            if (gr < nrows) {
#pragma unroll
                for (int j = 0; j < 3; j++) {
                    const int gc = j*16 + lm;
                    if (gc < GCN_NCLASS)
                        out[(size_t)gr * GCN_NCLASS + gc] = (bf16_t)acc[i][j][reg];
                }
            }
        }
    }
}

// ---- spmm2 + bias + log_softmax -> out[N,40] fp32 (R4 version) -------------
__global__ __launch_bounds__(256) void k_spmm2_lsm(
    const int* __restrict__ row_ptr, const int* __restrict__ col,
    const float* __restrict__ val, const unsigned int* __restrict__ sup2,
    const float* __restrict__ b2, float* __restrict__ out, int nrows)
{
    const int wid  = (blockIdx.x * blockDim.x + threadIdx.x) >> 6;
    const int lane = threadIdx.x & 63;
    const int g    = lane / 20;            // 0..2 valid, 3 = idle lanes 60-63
    const int li   = lane - g * 20;
    const int r    = wid * 3 + g;
    const bool active = (g < 3) && (r < nrows);

    int e0 = 0, e1 = 0;
    if (active) { e0 = row_ptr[r]; e1 = row_ptr[r + 1]; }

    float ax = 0.f, ay = 0.f;
    int e = e0;
    for (; e + 3 < e1; e += 4) {
        const int c0 = col[e],   c1 = col[e+1], c2 = col[e+2], c3 = col[e+3];
        const float v0 = val[e], v1 = val[e+1], v2 = val[e+2], v3 = val[e+3];
        const unsigned int u0 = sup2[(unsigned)(c0 * 20) + li];
        const unsigned int u1 = sup2[(unsigned)(c1 * 20) + li];
        const unsigned int u2 = sup2[(unsigned)(c2 * 20) + li];
        const unsigned int u3 = sup2[(unsigned)(c3 * 20) + li];
        ax = fmaf(v0, blo(u0), ax); ay = fmaf(v0, bhi(u0), ay);
        ax = fmaf(v1, blo(u1), ax); ay = fmaf(v1, bhi(u1), ay);
        ax = fmaf(v2, blo(u2), ax); ay = fmaf(v2, bhi(u2), ay);
        ax = fmaf(v3, blo(u3), ax); ay = fmaf(v3, bhi(u3), ay);
    }
    for (; e < e1; e++) {
        const unsigned int u = sup2[(unsigned)(col[e] * 20) + li];
        const float v = val[e];
        ax = fmaf(v, blo(u), ax); ay = fmaf(v, bhi(u), ay);
    }

    float l0 = -INFINITY, l1 = -INFINITY;
    if (active) {
        l0 = ax + b2[li * 2];
        l1 = ay + b2[li * 2 + 1];
    }

    // group-local (20-lane) shuffle reductions
    float m = fmaxf(l0, l1);
#pragma unroll
    for (int off = 16; off >= 1; off >>= 1) {
        const float t = __shfl_down(m, off, 64);
        if (li + off < 20) m = fmaxf(m, t);
    }
    m = __shfl(m, g * 20, 64);   // broadcast group max

    float s = active ? (__expf(l0 - m) + __expf(l1 - m)) : 0.f;
#pragma unroll
    for (int off = 16; off >= 1; off >>= 1) {
        const float t = __shfl_down(s, off, 64);
        if (li + off < 20) s += t;
    }
    s = __shfl(s, g * 20, 64);

    if (active) {
        const float lse = m + __logf(s);
        float* p = out + (size_t)r * GCN_NCLASS + li * 2;
        p[0] = l0 - lse;
        p[1] = l1 - lse;
    }
}

// ---------------------------------------------------------------------------
extern "C" void kernel_launch(void* const* d_in, const int* in_sizes, int n_in,
                              void* d_out, int out_size, void* d_ws, size_t ws_size,
                              hipStream_t stream)
{
    const float* x       = (const float*)d_in[0];
    const int*   adj_row = (const int*)  d_in[1];
    const int*   adj_col = (const int*)  d_in[2];
    const float* adj_val = (const float*)d_in[3];
    // d_in[4] = i (unused)
    const float* W1 = (const float*)d_in[5];
    const float* b1 = (const float*)d_in[6];
    const float* W2 = (const float*)d_in[7];
    const float* b2 = (const float*)d_in[8];
    float* out = (float*)d_out;

    const int N = in_sizes[0] / GCN_NFEAT;   // 100000
    const int E = in_sizes[1];               // 3200000

    // workspace layout (1 KiB aligned chunks)
    char* ws = (char*)d_ws;
    size_t off = 0;
    int* row_ptr = (int*)(ws + off);
    off += (((size_t)(N + 1) * sizeof(int)) + 1023) & ~(size_t)1023;
    bf16_t* w1t = (bf16_t*)(ws + off);                 // 128*256 bf16
    off += ((size_t)GCN_NHID * GCN_NFEAT * 2 + 1023) & ~(size_t)1023;
    bf16_t* w2t = (bf16_t*)(ws + off);                 // 48*128 bf16
    off += ((size_t)48 * GCN_NHID * 2 + 1023) & ~(size_t)1023;
    bf16_t* sup1p = (bf16_t*)(ws + off);               // [8][N][16] bf16 panel-major
    off += ((size_t)N * GCN_NHID * 2 + 1023) & ~(size_t)1023;
    bf16_t* h = (bf16_t*)(ws + off);                   // N*128 bf16 row-major
    bf16_t* sup2 = sup1p;                              // reuse sup1p region (N*40 bf16)

    k_row_ptr<<<(N + 1 + 255) / 256, 256, 0, stream>>>(adj_row, row_ptr, N, E);
    k_prep_w1t<<<GCN_NHID * GCN_NFEAT / 256, 256, 0, stream>>>(W1, w1t);
    k_prep_w2t<<<(48 * GCN_NHID + 255) / 256, 256, 0, stream>>>(W2, w2t);
    k_gemm1<<<(N + 127) / 128, 256, 0, stream>>>(x, w1t, sup1p, N);
    const int nblk1 = ((N + 3) / 4) * 8;               // (row-chunk, panel) blocks
    k_spmm1<<<nblk1, 256, 0, stream>>>(row_ptr, adj_col, adj_val,
                                       (const unsigned int*)sup1p, b1,
                                       (unsigned int*)h, N);
    k_gemm2<<<(N + 127) / 128, 256, 0, stream>>>(h, w2t, sup2, N);
    const int nw2 = (N + 2) / 3;                       // waves for spmm2 (3 rows/wave)
    k_spmm2_lsm<<<(nw2 + 3) / 4, 256, 0, stream>>>(row_ptr, adj_col, adj_val,
                                                   (const unsigned int*)sup2, b2, out, N);
}